// Round 16
// baseline (345.908 us; speedup 1.0000x reference)
//
#include <hip/hip_runtime.h>
#include <hip/hip_bf16.h>
#include <stdint.h>

#define ALPHA 1.0f

typedef __attribute__((ext_vector_type(8))) short bf16x8;
typedef __attribute__((ext_vector_type(4))) float f32x4;
typedef unsigned short ushort_t;

__device__ __forceinline__ unsigned short f32_to_bf16_rne(float f) {
    union { float f; unsigned int u; } v; v.f = f;
    unsigned int u = v.u;
    unsigned int r = u + 0x7FFFu + ((u >> 16) & 1u);
    return (unsigned short)(r >> 16);
}

__device__ __forceinline__ unsigned int cvt_pk_bf16(float lo, float hi) {
    unsigned int r;
    asm("v_cvt_pk_bf16_f32 %0, %1, %2" : "=v"(r) : "v"(lo), "v"(hi));
    return r;
}

__device__ __forceinline__ void async_copy16(const void* g, void* l) {
    __builtin_amdgcn_global_load_lds(
        (const __attribute__((address_space(1))) void*)g,
        (__attribute__((address_space(3))) void*)l, 16, 0, 0);
}

// ---------------------------------------------------------------------------
// Fused W_eff: weff[o][i] = W[o][i] + ALPHA * sum_r fac[o][r] * t1[r][i]
template <bool BF16OUT>
__global__ __launch_bounds__(256)
void weff_fused_kernel(const float* __restrict__ W,
                       const float* __restrict__ lora_down,
                       const float* __restrict__ lora_up,
                       const float* __restrict__ down_aux,
                       const float* __restrict__ up_aux,
                       void* __restrict__ weff) {
    int o = blockIdx.x;
    int i0 = threadIdx.x * 4;

    float fac[4] = {0.f, 0.f, 0.f, 0.f};
    for (int u = 0; u < 50; ++u) {
        float ua = up_aux[o * 50 + u] * ALPHA;
#pragma unroll
        for (int r = 0; r < 4; ++r) fac[r] += ua * lora_up[u * 4 + r];
    }

    float4 t1[4];
#pragma unroll
    for (int r = 0; r < 4; ++r) t1[r] = make_float4(0.f, 0.f, 0.f, 0.f);
    for (int d = 0; d < 100; ++d) {
        float4 da = *(const float4*)(down_aux + d * 1024 + i0);
#pragma unroll
        for (int r = 0; r < 4; ++r) {
            float ld = lora_down[r * 100 + d];
            t1[r].x += ld * da.x; t1[r].y += ld * da.y;
            t1[r].z += ld * da.z; t1[r].w += ld * da.w;
        }
    }

    float4 acc = *(const float4*)(W + (long)o * 1024 + i0);
#pragma unroll
    for (int r = 0; r < 4; ++r) {
        acc.x += fac[r] * t1[r].x; acc.y += fac[r] * t1[r].y;
        acc.z += fac[r] * t1[r].z; acc.w += fac[r] * t1[r].w;
    }

    if (BF16OUT) {
        ushort4 rr;
        rr.x = f32_to_bf16_rne(acc.x); rr.y = f32_to_bf16_rne(acc.y);
        rr.z = f32_to_bf16_rne(acc.z); rr.w = f32_to_bf16_rne(acc.w);
        *(ushort4*)((ushort_t*)weff + (long)o * 1024 + i0) = rr;
    } else {
        *(float4*)((float*)weff + (long)o * 1024 + i0) = acc;
    }
}

// ---------------------------------------------------------------------------
// Fused GEMM: C = cvt_bf16(A_f32[M][K]) * Bt_bf16[N][K]^T + bias
// 256x128 tile, BK=32, 8 waves (4Mx2N), per-wave 64x64 = acc[4][4] f32x4.
// KEY CHANGE (R16): sized for 2 BLOCKS/CU (cross-block TLP — the only lever
// that moved the barrier-lockstep stall in 15 rounds):
//   LDS 48 KB (Ab 2x16KB dbuf + Bb 2x8KB dbuf), acc 64 AGPR, total regs
//   targeted <=128 via __launch_bounds__(512,4) -> 16 waves/CU.
// Counted-vmcnt raw barriers, FIFO audit per wave (steady state, iter j):
//   start: [A(j+1) 4, B(j+1) 1]
//   frag reads (8 b128) -> 16 MFMA
//   writeA(o): waits vmcnt(1) = A(j+1), aged 1 full iter -> no stall
//   B2 barrier (all buf-c reads consumed by MFMA before here)
//   loadA(j+2) 4; stageB(j+2->Bb[c]) 1  -> [B(j+1), A(j+2) 4, B(j+2)]
//   gate: vmcnt(5) lgkmcnt(0) -> retires B(j+1) (aged 1 iter, L2-hot); B0
// Swizzle (BK=32 -> 4 chunks/row): key(row) = (row>>1)&3; quarter-wave's 16
// rows -> 8 bank-groups, 2 lanes/bank = free (m136). Same key on write
// (A: swizzled ds_write; B: pre-swizzled glds source) and fragment reads.
#define BM2 256
#define BN2 128
#define BK2 32

__global__ __launch_bounds__(512, 4)
void gemm_fused_kernel(const float* __restrict__ A,
                       const ushort_t* __restrict__ Bt,
                       const float* __restrict__ bias,
                       float* __restrict__ C, int M, int N, int K) {
    __shared__ __align__(16) ushort_t Ab[2][BM2 * BK2];  // 2 x 16 KB
    __shared__ __align__(16) ushort_t Bb[2][BN2 * BK2];  // 2 x 8 KB

    int nTilesN = N / BN2;  // 8
    int nwg = gridDim.x;
    int bid = blockIdx.x;
    int swz = bid;
    if ((nwg & 7) == 0) {   // grid = 2048 -> bijective XCD swizzle
        int cpx = nwg >> 3;
        swz = (bid & 7) * cpx + (bid >> 3);
    }
    int tm = swz / nTilesN;   // 8 consecutive swz on one XCD share an A panel
    int tn = swz % nTilesN;
    const long rowA0 = (long)tm * BM2;
    const long colB0 = (long)tn * BN2;

    int tid = threadIdx.x;
    int lane = tid & 63;
    int wave = tid >> 6;     // 0..7
    int wr = wave >> 1;      // 0..3  (M)
    int wc = wave & 1;       // 0..1  (N)

    // ---- A staging map: row ar = tid>>1 (0..255), half h = tid&1 ----
    //   16 f32 at k = h*16 -> two bf16 16B chunks (2h, 2h+1), swizzled.
    int ar = tid >> 1;
    int ah = tid & 1;
    int keyA = (ar >> 1) & 3;
    int sA0 = (2 * ah) ^ keyA;
    int sA1 = (2 * ah + 1) ^ keyA;

    // ---- B staging map (1 glds/thread, pre-swizzled source) ----
    int brow = tid >> 2;                     // 0..127
    int bcol = (tid & 3) ^ ((brow >> 1) & 3);

    // ---- fragment map ----
    int fr = lane & 15;
    int h4 = lane >> 4;                      // 0..3
    int fchunk = (h4 ^ ((fr >> 1) & 3)) * 8; // element offset in 32-elem row
    int aoff = (wr * 64 + fr) * BK2;
    int boff = (wc * 64 + fr) * BK2;

    f32x4 acc[4][4];
#pragma unroll
    for (int m = 0; m < 4; ++m)
#pragma unroll
        for (int n = 0; n < 4; ++n) acc[m][n] = (f32x4)(0.0f);

    const int nIter = K / BK2;   // 32

    float4 vA0, vA1, vA2, vA3;   // 16 regs: next A tile, 16 f32/thread

    auto loadA = [&](int kt) {
        const float* p = A + (rowA0 + ar) * (long)K + kt * BK2 + ah * 16;
        vA0 = ((const float4*)p)[0];
        vA1 = ((const float4*)p)[1];
        vA2 = ((const float4*)p)[2];
        vA3 = ((const float4*)p)[3];
    };
    auto writeA = [&](int buf) {
        uint4 w1, w2;
        w1.x = cvt_pk_bf16(vA0.x, vA0.y);
        w1.y = cvt_pk_bf16(vA0.z, vA0.w);
        w1.z = cvt_pk_bf16(vA1.x, vA1.y);
        w1.w = cvt_pk_bf16(vA1.z, vA1.w);
        w2.x = cvt_pk_bf16(vA2.x, vA2.y);
        w2.y = cvt_pk_bf16(vA2.z, vA2.w);
        w2.z = cvt_pk_bf16(vA3.x, vA3.y);
        w2.w = cvt_pk_bf16(vA3.z, vA3.w);
        *(uint4*)&Ab[buf][ar * BK2 + sA0 * 8] = w1;
        *(uint4*)&Ab[buf][ar * BK2 + sA1 * 8] = w2;
    };
    auto stageB = [&](int kt, int buf) {
        const ushort_t* src =
            Bt + (colB0 + brow) * (long)K + kt * BK2 + bcol * 8;
        // linear dest: lane l of wave w -> chunk w*64+l -> offset (w*512+l*8)
        ushort_t* dst = &Bb[buf][wave * 512];
        async_copy16(src, dst);
    };

    // ---------------- prologue ----------------
    loadA(0);                 // [A0 4]
    stageB(0, 0);             // [A0 4, B0 1]
    writeA(0);                // waits vmcnt(1): one-time HBM stall
    loadA(1);                 // [B0 1, A1 4]
    stageB(1, 1);             // [B0 1, A1 4, B1 1]
    asm volatile("s_waitcnt vmcnt(5) lgkmcnt(0)" ::: "memory");  // B0 landed
    __builtin_amdgcn_s_barrier();

#pragma unroll 1
    for (int j = 0; j < nIter; ++j) {
        int c = j & 1, o = c ^ 1;
        bool s1 = (j + 1 < nIter);
        bool s2 = (j + 2 < nIter);

        // fragment reads (buf c)
        bf16x8 a[4], b[4];
#pragma unroll
        for (int m = 0; m < 4; ++m)
            a[m] = *(const bf16x8*)&Ab[c][aoff + m * 16 * BK2 + fchunk];
#pragma unroll
        for (int n = 0; n < 4; ++n)
            b[n] = *(const bf16x8*)&Bb[c][boff + n * 16 * BK2 + fchunk];

        // 16 MFMA
        __builtin_amdgcn_s_setprio(1);
#pragma unroll
        for (int m = 0; m < 4; ++m)
#pragma unroll
            for (int n = 0; n < 4; ++n)
                acc[m][n] = __builtin_amdgcn_mfma_f32_16x16x32_bf16(
                    a[m], b[n], acc[m][n], 0, 0, 0);
        __builtin_amdgcn_s_setprio(0);

        // cvt+write A(j+1) -> Ab[o]  (waits vmcnt(1): aged 1 iter, no stall)
        if (s1) writeA(o);

        __builtin_amdgcn_s_barrier();            // B2

        // next-generation VMEM: A(j+2) first, then B(j+2) (FIFO order keeps
        // writeA's wait at vmcnt(1) next iter)
        if (s2) {
            loadA(j + 2);
            stageB(j + 2, c);
        }

        // gate: retire B(j+1) (aged 1 iter); keep A(j+2)+B(j+2) in flight
        if (s2) {
            asm volatile("s_waitcnt vmcnt(5) lgkmcnt(0)" ::: "memory");
        } else if (s1) {
            asm volatile("s_waitcnt vmcnt(0) lgkmcnt(0)" ::: "memory");
        } else {
            asm volatile("s_waitcnt lgkmcnt(0)" ::: "memory");
        }
        __builtin_amdgcn_s_barrier();            // B0
    }

    // ---- epilogue: C = acc + bias ----
    int ccol = lane & 15;
    int crow = (lane >> 4) * 4;
#pragma unroll
    for (int m = 0; m < 4; ++m) {
        long grow = rowA0 + wr * 64 + m * 16 + crow;
#pragma unroll
        for (int n = 0; n < 4; ++n) {
            long gcol = colB0 + wc * 64 + n * 16 + ccol;
            float bb = bias[gcol];
#pragma unroll
            for (int r = 0; r < 4; ++r) {
                C[(grow + r) * N + gcol] = acc[m][n][r] + bb;
            }
        }
    }
}

// ---------------------------------------------------------------------------
// Fallback: plain f32 tiled GEMM (used only if ws too small for bf16 path)
__global__ __launch_bounds__(256)
void gemm_f32_fallback(const float* __restrict__ A, const float* __restrict__ Bt,
                       const float* __restrict__ bias, float* __restrict__ C,
                       int M, int N, int K) {
    __shared__ float As[64][17];
    __shared__ float Bs[64][17];
    int tilesN = N / 64;
    int tm = blockIdx.x / tilesN;
    int tn = blockIdx.x % tilesN;
    int tid = threadIdx.x;
    int tr = tid / 16, tc = tid % 16;
    float acc[4][4] = {};
    for (int k0 = 0; k0 < K; k0 += 16) {
        for (int t = tid; t < 64 * 16; t += 256) {
            int r = t / 16, c = t % 16;
            As[r][c] = A[((long)tm * 64 + r) * K + k0 + c];
            Bs[r][c] = Bt[((long)tn * 64 + r) * K + k0 + c];
        }
        __syncthreads();
#pragma unroll
        for (int kk = 0; kk < 16; ++kk) {
            float av[4], bv[4];
#pragma unroll
            for (int i = 0; i < 4; ++i) av[i] = As[tr * 4 + i][kk];
#pragma unroll
            for (int j = 0; j < 4; ++j) bv[j] = Bs[tc * 4 + j][kk];
#pragma unroll
            for (int i = 0; i < 4; ++i)
#pragma unroll
                for (int j = 0; j < 4; ++j) acc[i][j] += av[i] * bv[j];
        }
        __syncthreads();
    }
#pragma unroll
    for (int i = 0; i < 4; ++i) {
        long row = (long)tm * 64 + tr * 4 + i;
#pragma unroll
        for (int j = 0; j < 4; ++j) {
            long col = (long)tn * 64 + tc * 4 + j;
            C[row * N + col] = acc[i][j] + bias[col];
        }
    }
}

// ---------------------------------------------------------------------------
extern "C" void kernel_launch(void* const* d_in, const int* in_sizes, int n_in,
                              void* d_out, int out_size, void* d_ws, size_t ws_size,
                              hipStream_t stream) {
    const float* hs        = (const float*)d_in[0];
    const float* W         = (const float*)d_in[1];
    const float* b         = (const float*)d_in[2];
    const float* lora_down = (const float*)d_in[3];
    const float* lora_up   = (const float*)d_in[4];
    const float* down_aux  = (const float*)d_in[5];
    const float* up_aux    = (const float*)d_in[6];
    float* out = (float*)d_out;

    const int K = 1024;   // IN
    const int N = 1024;   // OUT
    const int M = in_sizes[0] / K;  // B*S = 65536

    char* ws = (char*)d_ws;
    const size_t NEED_FAST = 2 * 1024 * 1024;   // weff bf16 only

    if (ws_size >= NEED_FAST && (M % BM2) == 0) {
        ushort_t* weff = (ushort_t*)ws;
        weff_fused_kernel<true><<<N, 256, 0, stream>>>(W, lora_down, lora_up,
                                                       down_aux, up_aux, weff);
        int grid = (M / BM2) * (N / BN2);   // 2048
        gemm_fused_kernel<<<grid, 512, 0, stream>>>(hs, weff, b, out, M, N, K);
    } else {
        float* weff = (float*)ws;  // 4MB
        weff_fused_kernel<false><<<N, 256, 0, stream>>>(W, lora_down, lora_up,
                                                        down_aux, up_aux, weff);
        int grid = (M / 64) * (N / 64);
        gemm_f32_fallback<<<grid, 256, 0, stream>>>(hs, weff, b, out, M, N, K);
    }
}